// Round 1
// baseline (976.417 us; speedup 1.0000x reference)
//
#include <hip/hip_runtime.h>
#include <stddef.h>

typedef unsigned short u16;
typedef unsigned int u32;

#define B_ 4
#define T_ 2048
#define C_ 1024
#define E_ 8
#define H_ 4096
#define NTOK (B_ * T_)     // 8192
#define NPAIR (NTOK * 2)   // 16384
#define BM 256
#define BN 128
#define BK 64              // k-tile (bf16 elements); row = 128 B
#define KSPLIT 2           // phase2 K-split (atomics make this free)
#define MAXTILES 72        // ceil((16384 + 8*255)/256)
#define MAXROWS (MAXTILES * BM)  // 18432

typedef __bf16 bf16x8 __attribute__((ext_vector_type(8)));
typedef float f32x4 __attribute__((ext_vector_type(4)));

__device__ __forceinline__ u16 f2bf(float f) {
    union { float f; u32 u; } c;
    c.f = f;
    u32 r = c.u + 0x7FFFu + ((c.u >> 16) & 1u);  // round-to-nearest-even
    return (u16)(r >> 16);
}

// async global->LDS, 16B per lane; LDS dest = wave-uniform base + lane*16
__device__ __forceinline__ void gld16(const void* g, void* l) {
    __builtin_amdgcn_global_load_lds(
        (const __attribute__((address_space(1))) u32*)g,
        (__attribute__((address_space(3))) u32*)l, 16, 0, 0);
}

// ---------------- LayerNorm: h = bf16(LN(x)), out = x; fused expert count ----
__global__ __launch_bounds__(256) void ln_kernel(
    const float* __restrict__ x, const float* __restrict__ gamma,
    const float* __restrict__ beta, float* __restrict__ out,
    u16* __restrict__ h, const int* __restrict__ winners,
    int* __restrict__ counts) {
    const int token = blockIdx.x;
    const int t = threadIdx.x;
    if (t < 2) atomicAdd(&counts[winners[token * 2 + t]], 1);
    const float* xr = x + (size_t)token * C_;
    float4 v = *(const float4*)(xr + t * 4);
    float s = v.x + v.y + v.z + v.w;
    float ss = v.x * v.x + v.y * v.y + v.z * v.z + v.w * v.w;
    #pragma unroll
    for (int off = 32; off > 0; off >>= 1) {
        s += __shfl_down(s, off);
        ss += __shfl_down(ss, off);
    }
    __shared__ float ws_s[4], ws_q[4];
    const int wave = t >> 6, lane = t & 63;
    if (lane == 0) { ws_s[wave] = s; ws_q[wave] = ss; }
    __syncthreads();
    float S = ws_s[0] + ws_s[1] + ws_s[2] + ws_s[3];
    float Q = ws_q[0] + ws_q[1] + ws_q[2] + ws_q[3];
    float mu = S * (1.0f / C_);
    float var = Q * (1.0f / C_) - mu * mu;
    float rstd = rsqrtf(var + 1e-5f);
    float4 g = *(const float4*)(gamma + t * 4);
    float4 b = *(const float4*)(beta + t * 4);
    ushort4 hv;
    hv.x = f2bf((v.x - mu) * rstd * g.x + b.x);
    hv.y = f2bf((v.y - mu) * rstd * g.y + b.y);
    hv.z = f2bf((v.z - mu) * rstd * g.z + b.z);
    hv.w = f2bf((v.w - mu) * rstd * g.w + b.w);
    *(float4*)(out + (size_t)token * C_ + t * 4) = v;  // out = x (residual base)
    *(ushort4*)(h + (size_t)token * C_ + t * 4) = hv;
}

// ---------------- Weight convert+transpose: fp32 [E][K][N] -> bf16 [E][N][K] --
// PERM: source k-row permuted per 64-block by phi(r)=((r&3)<<4)|(r>>2), matching
// the gemm1 epilogue's packed hidden layout (only used for W2).
template <bool PERM>
__global__ __launch_bounds__(256) void convert_transpose(
    const float* __restrict__ in, u16* __restrict__ outp, int K, int N) {
    const int e = blockIdx.z;
    const int k0 = blockIdx.y * 64, n0 = blockIdx.x * 64;
    const int tx = threadIdx.x & 15, ty = threadIdx.x >> 4;  // 16 x 16
    __shared__ float t[64][69];  // pitch 69: 2-way max bank aliasing on reads
    const float* src = in + (size_t)e * K * N;
    u16* dst = outp + (size_t)e * N * K;
    #pragma unroll
    for (int i = 0; i < 4; ++i) {
        int r = ty + i * 16;  // LDS row (= dst k-offset)
        int kr = PERM ? (((r & 3) << 4) | (r >> 2)) : r;  // src k-offset
        float4 v = *(const float4*)(src + (size_t)(k0 + kr) * N + n0 + tx * 4);
        t[r][tx * 4 + 0] = v.x;
        t[r][tx * 4 + 1] = v.y;
        t[r][tx * 4 + 2] = v.z;
        t[r][tx * 4 + 3] = v.w;
    }
    __syncthreads();
    #pragma unroll
    for (int i = 0; i < 4; ++i) {
        int nl = ty + i * 16;
        ushort4 o;
        o.x = f2bf(t[tx * 4 + 0][nl]);
        o.y = f2bf(t[tx * 4 + 1][nl]);
        o.z = f2bf(t[tx * 4 + 2][nl]);
        o.w = f2bf(t[tx * 4 + 3][nl]);
        *(ushort4*)(dst + (size_t)(n0 + nl) * K + k0 + tx * 4) = o;
    }
}

// ---------------- Expert bucketing (pad to BM=256) ----------------
__global__ void offsets_kernel(const int* __restrict__ counts, int* __restrict__ padded_off,
                               int* __restrict__ tile_expert) {
    if (threadIdx.x != 0 || blockIdx.x != 0) return;
    int off = 0;
    padded_off[0] = 0;
    for (int e = 0; e < E_; ++e) {
        off += ((counts[e] + 255) >> 8) << 8;
        padded_off[e + 1] = off;
    }
    for (int t = 0; t < MAXTILES; ++t) {
        int r = t * BM;
        int e = -1;
        if (r < off) {
            e = 0;
            while (r >= padded_off[e + 1]) ++e;
        }
        tile_expert[t] = e;
    }
}

__global__ void place_kernel(const int* __restrict__ winners, const float* __restrict__ wts,
                             const int* __restrict__ padded_off, int* __restrict__ pos,
                             int* __restrict__ token_id, float* __restrict__ pair_w) {
    int p = blockIdx.x * blockDim.x + threadIdx.x;
    if (p >= NPAIR) return;
    int e = winners[p];
    int slot = padded_off[e] + atomicAdd(&pos[e], 1);
    token_id[slot] = p >> 1;
    pair_w[slot] = wts[p];
}

// ---------------- Grouped GEMM: 256x128 tile, 8 waves, 3-buffer pipeline ------
// Phase-split K-loop with counted vmcnt (T3+T4), setprio around MFMA clusters
// (T5), both-sides XOR chunk swizzle (proven 0-conflict), XCD-bijective block
// swizzle (T1). Tile t+2 is staged during tile t's two phases; the per-tile
// s_waitcnt vmcnt(6) leaves the next tile's 6 loads in flight across the
// barrier (never drains to 0 in the main loop).
// PHASE2=false: hidden[r,:] = bf16(relu(h[tok(r)] @ W1T[e]^T)^2)  K=1024, N=4096
//               hidden K-dim stored permuted: p64 = lrow*4 + ni
// PHASE2=true : out[tok(r),:] += pair_w[r] * (hidden[r] @ W2T[e]^T) K=4096
//               (split over blockIdx.z in KSPLIT chunks; epilogue is atomic)
template <bool PHASE2>
__global__ __launch_bounds__(512, 2) void gemm_kernel(
    const u16* __restrict__ Amat, const u16* __restrict__ Bmat,
    const int* __restrict__ token_id, const float* __restrict__ pair_w,
    const int* __restrict__ tile_expert, u16* __restrict__ hidden,
    float* __restrict__ out, const u16* __restrict__ zeropage) {
    constexpr int PITCH = PHASE2 ? H_ : C_;           // row pitch of A and B
    constexpr int KRANGE = PHASE2 ? (H_ / KSPLIT) : C_;  // per-block K extent
    constexpr int NT = KRANGE / BK;                   // 32 or 16 k-tiles
    constexpr int NWGX = PHASE2 ? (C_ / BN) : (H_ / BN);  // 8 or 32
    constexpr int ABUF = BM * BK;                     // 16384 elems (32 KB)
    constexpr int BBUF = BN * BK;                     // 8192 elems  (16 KB)
    constexpr int BUFE = ABUF + BBUF;                 // 24576 elems (48 KB)

    // XCD-aware bijective swizzle: nwg = NWGX*MAXTILES is divisible by 8
    // (2304 / 576), so the simple chunked remap is bijective.
    int bid = blockIdx.y * NWGX + blockIdx.x;
    constexpr int NWG = NWGX * MAXTILES;
    bid = (bid & 7) * (NWG >> 3) + (bid >> 3);
    const int ct = bid % NWGX;
    const int rt = bid / NWGX;

    const int e = tile_expert[rt];
    if (e < 0) return;
    const int tid = threadIdx.x;
    const int w = tid >> 6;      // wave 0..7
    const int lane = tid & 63;
    const int sub = lane >> 3;
    const size_t koffB = (size_t)(((lane & 7) ^ sub) * 16);  // global-side swizzle
    const int n0 = ct * BN;
    const int kbase = PHASE2 ? blockIdx.z * KRANGE : 0;
    const u16* Bb = Bmat + (size_t)e * H_ * C_;
    const char* zp = (const char*)zeropage;

    // Staging geometry: A = 4 instr/thread (instr j covers block-rows
    // [j*64+w*8, +8)); B = 2 instr/thread. 6 gld16 per k-tile per thread.
    const char* abase[4];
    bool aval[4];
    const char* bbase[2];
    #pragma unroll
    for (int j = 0; j < 4; ++j) {
        const int grow = rt * BM + j * 64 + w * 8 + sub;
        if (PHASE2) {
            aval[j] = true;
            abase[j] = (const char*)(Amat + (size_t)grow * PITCH + kbase) + koffB;
        } else {
            int tok = token_id[grow];
            aval[j] = tok >= 0;
            abase[j] = (const char*)(Amat + (size_t)(tok < 0 ? 0 : tok) * PITCH) + koffB;
        }
    }
    #pragma unroll
    for (int j = 0; j < 2; ++j) {
        const int brow = n0 + j * 64 + w * 8 + sub;
        bbase[j] = (const char*)(Bb + (size_t)brow * PITCH + kbase) + koffB;
    }

    extern __shared__ u16 smem[];  // 3 * 48 KB = 144 KB

    const int wr = w >> 1, wc = w & 1;   // wave tile: rows wr*64, cols wc*64
    const int lrow = lane & 15;
    const int quad = lane >> 4;
    const int rsw = lrow & 7;            // read-side swizzle key

    f32x4 acc[4][4] = {};

#define SRCA(j_) ((kt < NT && aval[j_]) ? abase[j_] + (size_t)kt * 128 : zp)
#define SRCB(j_) ((kt < NT) ? bbase[j_] + (size_t)kt * 128 : zp)

    // Prologue: stage tile 0 -> buf0, tile 1 -> buf1 (12 loads in flight)
    #pragma unroll
    for (int kt = 0; kt < 2; ++kt) {
        u16* sb = smem + kt * BUFE;
        #pragma unroll
        for (int j = 0; j < 4; ++j)
            gld16(SRCA(j), sb + j * 4096 + w * 512);
        #pragma unroll
        for (int j = 0; j < 2; ++j)
            gld16(SRCB(j), sb + ABUF + j * 4096 + w * 512);
    }

    int c = 0, s = 2;
    for (int t = 0; t < NT; ++t) {
        // Tile t's 6 loads are the oldest; leave tile t+1's 6 in flight.
        asm volatile("s_waitcnt vmcnt(6)" ::: "memory");
        __builtin_amdgcn_s_barrier();
        __builtin_amdgcn_sched_barrier(0);
        const u16* cA = smem + c * BUFE;
        const u16* cB = cA + ABUF;
        u16* sb = smem + s * BUFE;  // buf of tile t-1, free as of the barrier
        const int kt = t + 2;

        // ---- phase 0: stage A chunks 0..2 of tile t+2; compute kk=0 ----
        gld16(SRCA(0), sb + 0 * 4096 + w * 512);
        gld16(SRCA(1), sb + 1 * 4096 + w * 512);
        gld16(SRCA(2), sb + 2 * 4096 + w * 512);
        {
            bf16x8 af[4], bfv[4];
            #pragma unroll
            for (int mi = 0; mi < 4; ++mi)
                af[mi] = *(const bf16x8*)&cA[(wr * 64 + mi * 16 + lrow) * BK +
                                             ((quad ^ rsw) * 8)];
            #pragma unroll
            for (int ni = 0; ni < 4; ++ni)
                bfv[ni] = *(const bf16x8*)&cB[(wc * 64 + ni * 16 + lrow) * BK +
                                              ((quad ^ rsw) * 8)];
            __builtin_amdgcn_s_setprio(1);
            #pragma unroll
            for (int mi = 0; mi < 4; ++mi)
                #pragma unroll
                for (int ni = 0; ni < 4; ++ni)
                    acc[mi][ni] = __builtin_amdgcn_mfma_f32_16x16x32_bf16(
                        af[mi], bfv[ni], acc[mi][ni], 0, 0, 0);
            __builtin_amdgcn_s_setprio(0);
        }
        __builtin_amdgcn_s_barrier();   // phase alignment (no data hazard here)
        __builtin_amdgcn_sched_barrier(0);

        // ---- phase 1: stage A chunk 3 + B chunks 0..1; compute kk=1 ----
        gld16(SRCA(3), sb + 3 * 4096 + w * 512);
        gld16(SRCB(0), sb + ABUF + 0 * 4096 + w * 512);
        gld16(SRCB(1), sb + ABUF + 1 * 4096 + w * 512);
        {
            bf16x8 af[4], bfv[4];
            #pragma unroll
            for (int mi = 0; mi < 4; ++mi)
                af[mi] = *(const bf16x8*)&cA[(wr * 64 + mi * 16 + lrow) * BK +
                                             ((((4 + quad) ^ rsw)) * 8)];
            #pragma unroll
            for (int ni = 0; ni < 4; ++ni)
                bfv[ni] = *(const bf16x8*)&cB[(wc * 64 + ni * 16 + lrow) * BK +
                                              ((((4 + quad) ^ rsw)) * 8)];
            __builtin_amdgcn_s_setprio(1);
            #pragma unroll
            for (int mi = 0; mi < 4; ++mi)
                #pragma unroll
                for (int ni = 0; ni < 4; ++ni)
                    acc[mi][ni] = __builtin_amdgcn_mfma_f32_16x16x32_bf16(
                        af[mi], bfv[ni], acc[mi][ni], 0, 0, 0);
            __builtin_amdgcn_s_setprio(0);
        }
        c = c == 2 ? 0 : c + 1;
        s = s == 2 ? 0 : s + 1;
    }
#undef SRCA
#undef SRCB
    // Drain trailing (zeropage) stages before the workgroup can retire.
    asm volatile("s_waitcnt vmcnt(0)" ::: "memory");

    if (!PHASE2) {
        // Packed store: per (mi,j)-row, lane's 4 ni-values go to permuted
        // k' = n0 + wc*64 + lrow*4 + ni  -> one ushort4 (8 B) store.
        #pragma unroll
        for (int mi = 0; mi < 4; ++mi) {
            const int rbase = rt * BM + wr * 64 + mi * 16 + quad * 4;
            #pragma unroll
            for (int j = 0; j < 4; ++j) {
                ushort4 o;
                float v0 = fmaxf(acc[mi][0][j], 0.0f);
                float v1 = fmaxf(acc[mi][1][j], 0.0f);
                float v2 = fmaxf(acc[mi][2][j], 0.0f);
                float v3 = fmaxf(acc[mi][3][j], 0.0f);
                o.x = f2bf(v0 * v0);
                o.y = f2bf(v1 * v1);
                o.z = f2bf(v2 * v2);
                o.w = f2bf(v3 * v3);
                *(ushort4*)&hidden[(size_t)(rbase + j) * H_ + n0 + wc * 64 + lrow * 4] = o;
            }
        }
    } else {
        #pragma unroll
        for (int mi = 0; mi < 4; ++mi) {
            const int rbase = rt * BM + wr * 64 + mi * 16 + quad * 4;
            #pragma unroll
            for (int j = 0; j < 4; ++j) {
                const int grow = rbase + j;
                const int tok = token_id[grow];
                if (tok < 0) continue;
                const float pw = pair_w[grow];
                #pragma unroll
                for (int ni = 0; ni < 4; ++ni) {
                    const int col = n0 + wc * 64 + ni * 16 + lrow;
                    atomicAdd(&out[(size_t)tok * C_ + col], pw * acc[mi][ni][j]);
                }
            }
        }
    }
}

// ---------------- Launch ----------------
extern "C" void kernel_launch(void* const* d_in, const int* in_sizes, int n_in,
                              void* d_out, int out_size, void* d_ws, size_t ws_size,
                              hipStream_t stream) {
    const float* x = (const float*)d_in[0];
    const float* weights = (const float*)d_in[1];
    const float* gamma = (const float*)d_in[2];
    const float* beta = (const float*)d_in[3];
    const float* W1 = (const float*)d_in[4];
    const float* W2 = (const float*)d_in[5];
    const int* winners = (const int*)d_in[6];
    float* out = (float*)d_out;

    char* ws = (char*)d_ws;
    const size_t SZ_H = (size_t)NTOK * C_ * 2;           // 16 MB
    const size_t SZ_HID = (size_t)MAXROWS * H_ * 2;      // 151 MB
    const size_t SZ_WT = (size_t)E_ * H_ * C_ * 2;       // 64 MB each
    const size_t OFF_HID = SZ_H;
    const size_t OFF_W1T = OFF_HID + SZ_HID;
    const size_t OFF_W2T = OFF_W1T + SZ_WT;
    const size_t OFF_META = OFF_W2T + SZ_WT;

    u16* h = (u16*)ws;
    u16* hidden = (u16*)(ws + OFF_HID);
    u16* W1T = (u16*)(ws + OFF_W1T);
    u16* W2T = (u16*)(ws + OFF_W2T);
    int* meta = (int*)(ws + OFF_META);
    int* counts = meta;            // [0,8)
    int* pos = meta + 8;           // [8,16)
    int* padded_off = meta + 16;   // [16,32)
    u16* zeropage = (u16*)(meta + 32);  // [32,48) 64 B, 16B-aligned
    int* tile_expert = meta + 48;  // [48,120)
    int* token_id = meta + 192;
    float* pair_w = (float*)(meta + 192 + MAXROWS);

    constexpr int GEMM_LDS = 3 * (BM * BK + BN * BK) * 2;  // 147456 B
    static int attr_done = 0;
    if (!attr_done) {
        hipFuncSetAttribute(reinterpret_cast<const void*>(&gemm_kernel<false>),
                            hipFuncAttributeMaxDynamicSharedMemorySize, GEMM_LDS);
        hipFuncSetAttribute(reinterpret_cast<const void*>(&gemm_kernel<true>),
                            hipFuncAttributeMaxDynamicSharedMemorySize, GEMM_LDS);
        attr_done = 1;
    }

    hipMemsetAsync(meta, 0, 192 * sizeof(int), stream);
    hipMemsetAsync(token_id, 0xFF, (size_t)MAXROWS * sizeof(int), stream);

    ln_kernel<<<NTOK, 256, 0, stream>>>(x, gamma, beta, out, h, winners, counts);
    convert_transpose<false><<<dim3(H_ / 64, C_ / 64, E_), 256, 0, stream>>>(W1, W1T, C_, H_);
    convert_transpose<true><<<dim3(C_ / 64, H_ / 64, E_), 256, 0, stream>>>(W2, W2T, H_, C_);
    offsets_kernel<<<1, 64, 0, stream>>>(counts, padded_off, tile_expert);
    place_kernel<<<NPAIR / 256, 256, 0, stream>>>(winners, weights, padded_off, pos,
                                                  token_id, pair_w);
    gemm_kernel<false><<<dim3(H_ / BN, MAXTILES), 512, GEMM_LDS, stream>>>(
        h, W1T, token_id, pair_w, tile_expert, hidden, nullptr, zeropage);
    gemm_kernel<true><<<dim3(C_ / BN, MAXTILES, KSPLIT), 512, GEMM_LDS, stream>>>(
        hidden, W2T, token_id, pair_w, tile_expert, nullptr, out, zeropage);
}

// Round 2
// 902.284 us; speedup vs baseline: 1.0822x; 1.0822x over previous
//
#include <hip/hip_runtime.h>
#include <stddef.h>

typedef unsigned short u16;
typedef unsigned int u32;

#define B_ 4
#define T_ 2048
#define C_ 1024
#define E_ 8
#define H_ 4096
#define NTOK (B_ * T_)     // 8192
#define NPAIR (NTOK * 2)   // 16384
#define BM 128
#define BN 128
#define BK 64              // k-tile (bf16 elements); row = 128 B
#define KSPLIT 2           // phase2 K-split (atomics make this free)
#define MAXTILES 136       // ceil((16384 + 8*127)/128)
#define MAXROWS (MAXTILES * 128)  // 17408

typedef __bf16 bf16x8 __attribute__((ext_vector_type(8)));
typedef float f32x4 __attribute__((ext_vector_type(4)));

__device__ __forceinline__ u16 f2bf(float f) {
    union { float f; u32 u; } c;
    c.f = f;
    u32 r = c.u + 0x7FFFu + ((c.u >> 16) & 1u);  // round-to-nearest-even
    return (u16)(r >> 16);
}

// async global->LDS, 16B per lane; LDS dest = wave-uniform base + lane*16
__device__ __forceinline__ void gld16(const void* g, void* l) {
    __builtin_amdgcn_global_load_lds(
        (const __attribute__((address_space(1))) u32*)g,
        (__attribute__((address_space(3))) u32*)l, 16, 0, 0);
}

// ---------------- LayerNorm: h = bf16(LN(x)), out = x; fused expert count ----
__global__ __launch_bounds__(256) void ln_kernel(
    const float* __restrict__ x, const float* __restrict__ gamma,
    const float* __restrict__ beta, float* __restrict__ out,
    u16* __restrict__ h, const int* __restrict__ winners,
    int* __restrict__ counts) {
    const int token = blockIdx.x;
    const int t = threadIdx.x;
    if (t < 2) atomicAdd(&counts[winners[token * 2 + t]], 1);
    const float* xr = x + (size_t)token * C_;
    float4 v = *(const float4*)(xr + t * 4);
    float s = v.x + v.y + v.z + v.w;
    float ss = v.x * v.x + v.y * v.y + v.z * v.z + v.w * v.w;
    #pragma unroll
    for (int off = 32; off > 0; off >>= 1) {
        s += __shfl_down(s, off);
        ss += __shfl_down(ss, off);
    }
    __shared__ float ws_s[4], ws_q[4];
    const int wave = t >> 6, lane = t & 63;
    if (lane == 0) { ws_s[wave] = s; ws_q[wave] = ss; }
    __syncthreads();
    float S = ws_s[0] + ws_s[1] + ws_s[2] + ws_s[3];
    float Q = ws_q[0] + ws_q[1] + ws_q[2] + ws_q[3];
    float mu = S * (1.0f / C_);
    float var = Q * (1.0f / C_) - mu * mu;
    float rstd = rsqrtf(var + 1e-5f);
    float4 g = *(const float4*)(gamma + t * 4);
    float4 b = *(const float4*)(beta + t * 4);
    ushort4 hv;
    hv.x = f2bf((v.x - mu) * rstd * g.x + b.x);
    hv.y = f2bf((v.y - mu) * rstd * g.y + b.y);
    hv.z = f2bf((v.z - mu) * rstd * g.z + b.z);
    hv.w = f2bf((v.w - mu) * rstd * g.w + b.w);
    *(float4*)(out + (size_t)token * C_ + t * 4) = v;  // out = x (residual base)
    *(ushort4*)(h + (size_t)token * C_ + t * 4) = hv;
}

// ---------------- Weight convert+transpose: fp32 [E][K][N] -> bf16 [E][N][K] --
// PERM: source k-row permuted per 64-block by phi(r)=((r&3)<<4)|(r>>2), matching
// the gemm1 epilogue's packed hidden layout (only used for W2).
template <bool PERM>
__global__ __launch_bounds__(256) void convert_transpose(
    const float* __restrict__ in, u16* __restrict__ outp, int K, int N) {
    const int e = blockIdx.z;
    const int k0 = blockIdx.y * 64, n0 = blockIdx.x * 64;
    const int tx = threadIdx.x & 15, ty = threadIdx.x >> 4;  // 16 x 16
    __shared__ float t[64][69];  // pitch 69: 2-way max bank aliasing on reads
    const float* src = in + (size_t)e * K * N;
    u16* dst = outp + (size_t)e * N * K;
    #pragma unroll
    for (int i = 0; i < 4; ++i) {
        int r = ty + i * 16;  // LDS row (= dst k-offset)
        int kr = PERM ? (((r & 3) << 4) | (r >> 2)) : r;  // src k-offset
        float4 v = *(const float4*)(src + (size_t)(k0 + kr) * N + n0 + tx * 4);
        t[r][tx * 4 + 0] = v.x;
        t[r][tx * 4 + 1] = v.y;
        t[r][tx * 4 + 2] = v.z;
        t[r][tx * 4 + 3] = v.w;
    }
    __syncthreads();
    #pragma unroll
    for (int i = 0; i < 4; ++i) {
        int nl = ty + i * 16;
        ushort4 o;
        o.x = f2bf(t[tx * 4 + 0][nl]);
        o.y = f2bf(t[tx * 4 + 1][nl]);
        o.z = f2bf(t[tx * 4 + 2][nl]);
        o.w = f2bf(t[tx * 4 + 3][nl]);
        *(ushort4*)(dst + (size_t)(n0 + nl) * K + k0 + tx * 4) = o;
    }
}

// ---------------- Expert bucketing ----------------
// Parallelized: thread 0 does the 8-expert prefix into shared, then 136
// threads fill tile_expert concurrently (the old single-thread loop was
// ~144 dependent global round-trips of pure latency).
__global__ __launch_bounds__(256) void offsets_kernel(
    const int* __restrict__ counts, int* __restrict__ padded_off,
    int* __restrict__ tile_expert) {
    __shared__ int po[E_ + 1];
    if (threadIdx.x == 0) {
        int off = 0;
        po[0] = 0;
        padded_off[0] = 0;
        for (int e = 0; e < E_; ++e) {
            off += ((counts[e] + 127) >> 7) << 7;
            po[e + 1] = off;
            padded_off[e + 1] = off;
        }
    }
    __syncthreads();
    const int t = threadIdx.x;
    if (t < MAXTILES) {
        int r = t * 128;
        int e = -1;
        if (r < po[E_]) {
            e = 0;
            while (r >= po[e + 1]) ++e;
        }
        tile_expert[t] = e;
    }
}

__global__ void place_kernel(const int* __restrict__ winners, const float* __restrict__ wts,
                             const int* __restrict__ padded_off, int* __restrict__ pos,
                             int* __restrict__ token_id, float* __restrict__ pair_w) {
    int p = blockIdx.x * blockDim.x + threadIdx.x;
    if (p >= NPAIR) return;
    int e = winners[p];
    int slot = padded_off[e] + atomicAdd(&pos[e], 1);
    token_id[slot] = p >> 1;
    pair_w[slot] = wts[p];
}

// ---------------- Grouped GEMM, m97-style async staging + XOR swizzle ---------
// Round-0 proven structure (4 blocks/CU, implicit wave-level overlap) plus:
//  - T1 XCD-bijective block swizzle (validated round 1: FETCH 593->187 MB)
//  - PHASE2 K-split over blockIdx.z (epilogue is atomic, so free; fixes the
//    1088-block / 1024-concurrent ~47% tail)
// PHASE2=false: hidden[r,:] = bf16(relu(h[tok(r)] @ W1T[e]^T)^2)  K=1024, N=4096
//               hidden K-dim stored permuted: p64 = lrow*4 + ni
// PHASE2=true : out[tok(r),:] += pair_w[r] * (hidden[r] @ W2T[e]^T) K=4096/KSPLIT
template <bool PHASE2>
__global__ __launch_bounds__(256, 4) void gemm_kernel(
    const u16* __restrict__ Amat, const u16* __restrict__ Bmat,
    const int* __restrict__ token_id, const float* __restrict__ pair_w,
    const int* __restrict__ tile_expert, u16* __restrict__ hidden,
    float* __restrict__ out, const u16* __restrict__ zeropage) {
    constexpr int Kdim = PHASE2 ? H_ : C_;            // row pitch of A and B
    constexpr int KRANGE = PHASE2 ? (H_ / KSPLIT) : C_;  // per-block K extent
    constexpr int NWGX = PHASE2 ? (C_ / BN) : (H_ / BN); // 8 or 32
    constexpr int NWG = NWGX * MAXTILES;              // 1088 or 4352 (%8==0)

    // XCD-aware bijective swizzle: consecutive hw blocks land on different
    // XCDs; give each XCD a contiguous chunk of (rt, ct) space instead.
    int bid = blockIdx.y * NWGX + blockIdx.x;
    bid = (bid & 7) * (NWG >> 3) + (bid >> 3);
    const int ct = bid % NWGX;
    const int rt = bid / NWGX;

    const int e = tile_expert[rt];
    if (e < 0) return;
    const int tid = threadIdx.x;
    const int w = tid >> 6;      // wave 0..3
    const int lane = tid & 63;
    const int n0 = ct * BN;
    const int kbase = PHASE2 ? blockIdx.z * KRANGE : 0;
    const u16* Bb = Bmat + (size_t)e * H_ * C_;

    __shared__ u16 As[BM * BK];  // 16 KB, [row][k], row = 128 B
    __shared__ u16 Bs[BN * BK];  // 16 KB, [n][k]

    // Staging geometry: per wave, 4 instrs x (8 rows x 128 B) = 32 rows.
    // Lane i -> row sub = i>>3, k-chunk (16 B) = (i&7) ^ sub  (XOR swizzle;
    // LDS side is fixed lane*16, so we permute the GLOBAL side).
    const int sub = lane >> 3;
    const size_t koffB = (size_t)(((lane & 7) ^ sub) * 16);

    const char* abase[4];
    bool aval[4];
    const char* bbase[4];
    u16* adst[4];
    u16* bdst[4];
    #pragma unroll
    for (int j = 0; j < 4; ++j) {
        const int lrow32 = w * 32 + j * 8 + sub;
        const int grow = rt * BM + lrow32;
        if (PHASE2) {
            aval[j] = true;
            abase[j] = (const char*)(Amat + (size_t)grow * Kdim + kbase) + koffB;
        } else {
            int tok = token_id[grow];
            aval[j] = tok >= 0;
            abase[j] = (const char*)(Amat + (size_t)(tok < 0 ? 0 : tok) * Kdim) + koffB;
        }
        bbase[j] = (const char*)(Bb + (size_t)(n0 + lrow32) * Kdim + kbase) + koffB;
        adst[j] = &As[(w * 32 + j * 8) * BK];
        bdst[j] = &Bs[(w * 32 + j * 8) * BK];
    }

    const int wr = w >> 1, wc = w & 1;
    const int lrow = lane & 15;
    const int quad = lane >> 4;
    const int rsw = lrow & 7;  // read-side swizzle key

    f32x4 acc[4][4] = {};

    for (int k0 = 0; k0 < KRANGE; k0 += BK) {
        __syncthreads();
        const size_t kb = (size_t)k0 * 2;
        #pragma unroll
        for (int j = 0; j < 4; ++j)
            gld16(aval[j] ? abase[j] + kb : (const char*)zeropage, adst[j]);
        #pragma unroll
        for (int j = 0; j < 4; ++j)
            gld16(bbase[j] + kb, bdst[j]);
        __syncthreads();
        #pragma unroll
        for (int kk = 0; kk < 2; ++kk) {
            bf16x8 af[4], bfv[4];
            #pragma unroll
            for (int mi = 0; mi < 4; ++mi) {
                int row = wr * 64 + mi * 16 + lrow;
                int pch = (kk * 4 + quad) ^ rsw;
                af[mi] = *(const bf16x8*)&As[row * BK + pch * 8];
            }
            #pragma unroll
            for (int ni = 0; ni < 4; ++ni) {
                int row = wc * 64 + ni * 16 + lrow;
                int pch = (kk * 4 + quad) ^ rsw;
                bfv[ni] = *(const bf16x8*)&Bs[row * BK + pch * 8];
            }
            #pragma unroll
            for (int mi = 0; mi < 4; ++mi)
                #pragma unroll
                for (int ni = 0; ni < 4; ++ni)
                    acc[mi][ni] = __builtin_amdgcn_mfma_f32_16x16x32_bf16(
                        af[mi], bfv[ni], acc[mi][ni], 0, 0, 0);
        }
    }

    if (!PHASE2) {
        // Packed store: per (mi,j)-row, lane's 4 ni-values go to permuted
        // k' = n0 + wc*64 + lrow*4 + ni  -> one ushort4 (8 B) store.
        #pragma unroll
        for (int mi = 0; mi < 4; ++mi) {
            int rbase = rt * BM + wr * 64 + mi * 16 + quad * 4;
            #pragma unroll
            for (int j = 0; j < 4; ++j) {
                ushort4 o;
                float v0 = fmaxf(acc[mi][0][j], 0.0f);
                float v1 = fmaxf(acc[mi][1][j], 0.0f);
                float v2 = fmaxf(acc[mi][2][j], 0.0f);
                float v3 = fmaxf(acc[mi][3][j], 0.0f);
                o.x = f2bf(v0 * v0);
                o.y = f2bf(v1 * v1);
                o.z = f2bf(v2 * v2);
                o.w = f2bf(v3 * v3);
                *(ushort4*)&hidden[(size_t)(rbase + j) * H_ + n0 + wc * 64 + lrow * 4] = o;
            }
        }
    } else {
        #pragma unroll
        for (int mi = 0; mi < 4; ++mi) {
            int rbase = rt * BM + wr * 64 + mi * 16 + quad * 4;
            #pragma unroll
            for (int j = 0; j < 4; ++j) {
                int grow = rbase + j;
                int tok = token_id[grow];
                if (tok < 0) continue;
                float pw = pair_w[grow];
                #pragma unroll
                for (int ni = 0; ni < 4; ++ni) {
                    int col = n0 + wc * 64 + ni * 16 + lrow;
                    atomicAdd(&out[(size_t)tok * C_ + col], pw * acc[mi][ni][j]);
                }
            }
        }
    }
}

// ---------------- Launch ----------------
extern "C" void kernel_launch(void* const* d_in, const int* in_sizes, int n_in,
                              void* d_out, int out_size, void* d_ws, size_t ws_size,
                              hipStream_t stream) {
    const float* x = (const float*)d_in[0];
    const float* weights = (const float*)d_in[1];
    const float* gamma = (const float*)d_in[2];
    const float* beta = (const float*)d_in[3];
    const float* W1 = (const float*)d_in[4];
    const float* W2 = (const float*)d_in[5];
    const int* winners = (const int*)d_in[6];
    float* out = (float*)d_out;

    char* ws = (char*)d_ws;
    const size_t SZ_H = (size_t)NTOK * C_ * 2;           // 16 MB
    const size_t SZ_HID = (size_t)MAXROWS * H_ * 2;      // 136 MB
    const size_t SZ_WT = (size_t)E_ * H_ * C_ * 2;       // 64 MB each
    const size_t OFF_HID = SZ_H;
    const size_t OFF_W1T = OFF_HID + SZ_HID;
    const size_t OFF_W2T = OFF_W1T + SZ_WT;
    const size_t OFF_META = OFF_W2T + SZ_WT;

    u16* h = (u16*)ws;
    u16* hidden = (u16*)(ws + OFF_HID);
    u16* W1T = (u16*)(ws + OFF_W1T);
    u16* W2T = (u16*)(ws + OFF_W2T);
    int* meta = (int*)(ws + OFF_META);
    int* counts = meta;            // [0,8)
    int* pos = meta + 8;           // [8,16)
    int* padded_off = meta + 16;   // [16,32)
    u16* zeropage = (u16*)(meta + 32);  // [32,48) 64 B, 16B-aligned
    int* tile_expert = meta + 48;  // [48,184)
    int* token_id = meta + 192;
    float* pair_w = (float*)(meta + 192 + MAXROWS);

    hipMemsetAsync(meta, 0, 192 * sizeof(int), stream);
    hipMemsetAsync(token_id, 0xFF, (size_t)MAXROWS * sizeof(int), stream);

    ln_kernel<<<NTOK, 256, 0, stream>>>(x, gamma, beta, out, h, winners, counts);
    convert_transpose<false><<<dim3(H_ / 64, C_ / 64, E_), 256, 0, stream>>>(W1, W1T, C_, H_);
    convert_transpose<true><<<dim3(C_ / 64, H_ / 64, E_), 256, 0, stream>>>(W2, W2T, H_, C_);
    offsets_kernel<<<1, 256, 0, stream>>>(counts, padded_off, tile_expert);
    place_kernel<<<NPAIR / 256, 256, 0, stream>>>(winners, weights, padded_off, pos,
                                                  token_id, pair_w);
    gemm_kernel<false><<<dim3(H_ / BN, MAXTILES), 256, 0, stream>>>(
        h, W1T, token_id, pair_w, tile_expert, hidden, nullptr, zeropage);
    gemm_kernel<true><<<dim3(C_ / BN, MAXTILES, KSPLIT), 256, 0, stream>>>(
        hidden, W2T, token_id, pair_w, tile_expert, nullptr, out, zeropage);
}